// Round 1
// baseline (1429.173 us; speedup 1.0000x reference)
//
#include <hip/hip_runtime.h>
#include <hip/hip_bf16.h>

#define B_DIM 8
#define N_DIM 1024
#define C_DIM 768
#define H_DIM 12
#define HD    64
#define M_DIM (B_DIM * N_DIM)   // 8192

// ---------------------------------------------------------------------------
// GEMM: Out = X @ W^T (+ bias).  X: M x 768 row-major, W: 768 x 768 row-major
// out[m][d] = sum_c X[m][c] * W[d][c]
// MODE 0: Out[m][d] = dot + bias[d]                       (plain M x 768)
// MODE 1: Out laid out (B, H, n, hd): ((b*H + d/64)*1024 + n)*64 + d%64
// ---------------------------------------------------------------------------
template<int MODE>
__global__ __launch_bounds__(256)
void gemm_xwT(const float* __restrict__ X, const float* __restrict__ W,
              const float* __restrict__ bias, float* __restrict__ Out)
{
    __shared__ float As[16][68];   // [k][m], padded
    __shared__ float Bs[16][68];   // [k][n], padded

    const int tid = threadIdx.x;
    const int m0 = blockIdx.x * 64;
    const int n0 = blockIdx.y * 64;
    const int ty = tid >> 4, tx = tid & 15;
    const int lr = tid >> 2;            // 0..63  (row within tile)
    const int lc = (tid & 3) << 2;      // 0,4,8,12 (col within 16-wide k-slab)

    float acc[4][4] = {};

    for (int k0 = 0; k0 < C_DIM; k0 += 16) {
        float4 xa = *(const float4*)(X + (size_t)(m0 + lr) * C_DIM + k0 + lc);
        float4 wa = *(const float4*)(W + (size_t)(n0 + lr) * C_DIM + k0 + lc);
        As[lc+0][lr] = xa.x; As[lc+1][lr] = xa.y; As[lc+2][lr] = xa.z; As[lc+3][lr] = xa.w;
        Bs[lc+0][lr] = wa.x; Bs[lc+1][lr] = wa.y; Bs[lc+2][lr] = wa.z; Bs[lc+3][lr] = wa.w;
        __syncthreads();
        #pragma unroll
        for (int k = 0; k < 16; ++k) {
            float4 a4 = *(const float4*)&As[k][ty * 4];
            float4 b4 = *(const float4*)&Bs[k][tx * 4];
            float av[4] = {a4.x, a4.y, a4.z, a4.w};
            float bv[4] = {b4.x, b4.y, b4.z, b4.w};
            #pragma unroll
            for (int i = 0; i < 4; ++i)
                #pragma unroll
                for (int j = 0; j < 4; ++j)
                    acc[i][j] = fmaf(av[i], bv[j], acc[i][j]);
        }
        __syncthreads();
    }

    if (MODE == 0) {
        #pragma unroll
        for (int i = 0; i < 4; ++i) {
            int m = m0 + ty * 4 + i;
            float4 o;
            o.x = acc[i][0] + bias[n0 + tx*4 + 0];
            o.y = acc[i][1] + bias[n0 + tx*4 + 1];
            o.z = acc[i][2] + bias[n0 + tx*4 + 2];
            o.w = acc[i][3] + bias[n0 + tx*4 + 3];
            *(float4*)(Out + (size_t)m * C_DIM + n0 + tx * 4) = o;
        }
    } else {
        const int h = blockIdx.y;   // BN == hd == 64, so block col == head
        #pragma unroll
        for (int i = 0; i < 4; ++i) {
            int m = m0 + ty * 4 + i;
            int b = m >> 10, n = m & 1023;
            float4 o = make_float4(acc[i][0], acc[i][1], acc[i][2], acc[i][3]);
            *(float4*)(Out + ((size_t)(b * H_DIM + h) * N_DIM + n) * HD + tx * 4) = o;
        }
    }
}

// ---------------------------------------------------------------------------
// RoPE-2D in place on (B,H,N,64) tensors. One thread per rotation pair.
// dims [0,32) use pos[...,0]; dims [32,64) use pos[...,1].
// Within a 32-block: out[j] = t[j]*cos - t[j+16]*sin ; out[j+16] = t[j+16]*cos + t[j]*sin
// cos/sin of ang = pos * 100^(-j/16), j = 0..15
// ---------------------------------------------------------------------------
__global__ __launch_bounds__(256)
void rope_kernel(float* __restrict__ Qh, float* __restrict__ Kh,
                 const int* __restrict__ qpos, const int* __restrict__ kpos)
{
    const int PT = B_DIM * H_DIM * N_DIM * 32;   // pairs per tensor
    int gid = blockIdx.x * 256 + threadIdx.x;
    float* T; const int* P;
    if (gid >= PT) { T = Kh; P = kpos; gid -= PT; }
    else           { T = Qh; P = qpos; }

    int j   = gid & 15;
    int blk = (gid >> 4) & 1;
    int n   = (gid >> 5) & 1023;
    int h   = (gid >> 15) % H_DIM;
    int b   = gid / (32 * 1024 * H_DIM);

    float pos = (float)P[(b * N_DIM + n) * 2 + blk];
    // 100^(-j/16) = exp2(-j * log2(100)/16)
    float invf = exp2f(-(float)j * 0.41524101186092029f);
    float ang = pos * invf;
    float s, c;
    sincosf(ang, &s, &c);

    size_t base = ((size_t)(b * H_DIM + h) * N_DIM + n) * HD + blk * 32;
    float x1 = T[base + j];
    float x2 = T[base + j + 16];
    T[base + j]      = x1 * c - x2 * s;
    T[base + j + 16] = x2 * c + x1 * s;
}

// ---------------------------------------------------------------------------
// Flash attention (fp32). One block = one (b,h) x 64-row Q tile. 256 threads.
// Softmax state (m,l) kept in registers, replicated across the 16 lanes that
// own each row; reduced with __shfl_xor.
// ---------------------------------------------------------------------------
__global__ __launch_bounds__(256)
void flash_kernel(const float* __restrict__ Qh, const float* __restrict__ Kh,
                  const float* __restrict__ Vh, float* __restrict__ Xout)
{
    __shared__ float Qs[64][68];
    __shared__ float Ks[64][68];
    __shared__ float Vs[64][68];
    __shared__ float Ps[64][68];

    const int tid = threadIdx.x;
    const int bh  = blockIdx.y;          // 0..95
    const int q0  = blockIdx.x * 64;     // 0..960
    const int ty  = tid >> 4, tx = tid & 15;
    const size_t base = (size_t)bh * N_DIM * HD;

    // load Q tile (pre-scaled by hd^-0.5 = 0.125)
    #pragma unroll
    for (int l = 0; l < 4; ++l) {
        int f = tid + l * 256;
        int row = f >> 4, c4 = (f & 15) << 2;
        float4 v = *(const float4*)(Qh + base + (size_t)(q0 + row) * HD + c4);
        v.x *= 0.125f; v.y *= 0.125f; v.z *= 0.125f; v.w *= 0.125f;
        *(float4*)&Qs[row][c4] = v;
    }

    float acc[4][4] = {};
    float m_st[4] = {-3.0e38f, -3.0e38f, -3.0e38f, -3.0e38f};
    float l_st[4] = {};

    for (int kt = 0; kt < 16; ++kt) {
        // load K, V tiles
        #pragma unroll
        for (int l = 0; l < 4; ++l) {
            int f = tid + l * 256;
            int row = f >> 4, c4 = (f & 15) << 2;
            *(float4*)&Ks[row][c4] =
                *(const float4*)(Kh + base + (size_t)(kt * 64 + row) * HD + c4);
            *(float4*)&Vs[row][c4] =
                *(const float4*)(Vh + base + (size_t)(kt * 64 + row) * HD + c4);
        }
        __syncthreads();

        // S = Q K^T  (4x4 microtile per thread)
        float s[4][4] = {};
        for (int d = 0; d < 64; d += 4) {
            float qv[4][4], kv[4][4];
            #pragma unroll
            for (int i = 0; i < 4; ++i) {
                float4 t = *(const float4*)&Qs[ty*4 + i][d];
                qv[i][0] = t.x; qv[i][1] = t.y; qv[i][2] = t.z; qv[i][3] = t.w;
            }
            #pragma unroll
            for (int jj = 0; jj < 4; ++jj) {
                float4 t = *(const float4*)&Ks[tx*4 + jj][d];
                kv[jj][0] = t.x; kv[jj][1] = t.y; kv[jj][2] = t.z; kv[jj][3] = t.w;
            }
            #pragma unroll
            for (int i = 0; i < 4; ++i)
                #pragma unroll
                for (int jj = 0; jj < 4; ++jj)
                    s[i][jj] += qv[i][0]*kv[jj][0] + qv[i][1]*kv[jj][1]
                              + qv[i][2]*kv[jj][2] + qv[i][3]*kv[jj][3];
        }

        // online softmax, state in registers (replicated across 16 lanes/row)
        #pragma unroll
        for (int i = 0; i < 4; ++i) {
            int row = ty * 4 + i;
            float pm = fmaxf(fmaxf(s[i][0], s[i][1]), fmaxf(s[i][2], s[i][3]));
            #pragma unroll
            for (int mk = 1; mk < 16; mk <<= 1)
                pm = fmaxf(pm, __shfl_xor(pm, mk, 64));
            float mn = fmaxf(m_st[i], pm);
            float al = __expf(m_st[i] - mn);
            float p[4], rs = 0.f;
            #pragma unroll
            for (int jj = 0; jj < 4; ++jj) {
                p[jj] = __expf(s[i][jj] - mn);
                rs += p[jj];
                acc[i][jj] *= al;
            }
            #pragma unroll
            for (int mk = 1; mk < 16; mk <<= 1)
                rs += __shfl_xor(rs, mk, 64);
            l_st[i] = al * l_st[i] + rs;
            m_st[i] = mn;
            *(float4*)&Ps[row][tx * 4] = make_float4(p[0], p[1], p[2], p[3]);
        }
        // Ps rows are written and read only by the same wave's 16-lane group;
        // no cross-wave hazard -> no barrier needed here.

        // O += P @ V
        for (int k = 0; k < 64; k += 4) {
            float pv[4][4], vv[4][4];
            #pragma unroll
            for (int i = 0; i < 4; ++i) {
                float4 t = *(const float4*)&Ps[ty*4 + i][k];
                pv[i][0] = t.x; pv[i][1] = t.y; pv[i][2] = t.z; pv[i][3] = t.w;
            }
            #pragma unroll
            for (int kk = 0; kk < 4; ++kk) {
                float4 t = *(const float4*)&Vs[k + kk][tx * 4];
                vv[kk][0] = t.x; vv[kk][1] = t.y; vv[kk][2] = t.z; vv[kk][3] = t.w;
            }
            #pragma unroll
            for (int i = 0; i < 4; ++i)
                #pragma unroll
                for (int jj = 0; jj < 4; ++jj)
                    acc[i][jj] += pv[i][0]*vv[0][jj] + pv[i][1]*vv[1][jj]
                                + pv[i][2]*vv[2][jj] + pv[i][3]*vv[3][jj];
        }
        __syncthreads();   // protect Ks/Vs (and Ps) before next tile's loads
    }

    // normalize and write x in (B, N, C) layout
    const int b = bh / H_DIM, h = bh % H_DIM;
    #pragma unroll
    for (int i = 0; i < 4; ++i) {
        int row = ty * 4 + i;
        float inv = 1.0f / l_st[i];
        float4 o = make_float4(acc[i][0]*inv, acc[i][1]*inv, acc[i][2]*inv, acc[i][3]*inv);
        *(float4*)(Xout + ((size_t)(b * N_DIM) + q0 + row) * C_DIM + h * HD + tx * 4) = o;
    }
}

// ---------------------------------------------------------------------------
extern "C" void kernel_launch(void* const* d_in, const int* in_sizes, int n_in,
                              void* d_out, int out_size, void* d_ws, size_t ws_size,
                              hipStream_t stream)
{
    const float* query = (const float*)d_in[0];
    const float* key_  = (const float*)d_in[1];
    const float* value = (const float*)d_in[2];
    const int*   qpos  = (const int*)d_in[3];
    const int*   kpos  = (const int*)d_in[4];
    const float* Wq    = (const float*)d_in[5];
    const float* Wk    = (const float*)d_in[6];
    const float* Wv    = (const float*)d_in[7];
    const float* Wo    = (const float*)d_in[8];
    const float* bo    = (const float*)d_in[9];
    float* out = (float*)d_out;

    const size_t TEN = (size_t)B_DIM * H_DIM * N_DIM * HD;   // 6,291,456
    float* Qh = (float*)d_ws;
    float* Kh = Qh + TEN;
    float* Vh = Kh + TEN;
    float* Xb = Vh + TEN;   // (B, N, C) = same element count

    dim3 ggrid(M_DIM / 64, C_DIM / 64);   // 128 x 12
    gemm_xwT<1><<<ggrid, 256, 0, stream>>>(query, Wq, nullptr, Qh);
    gemm_xwT<1><<<ggrid, 256, 0, stream>>>(key_,  Wk, nullptr, Kh);
    gemm_xwT<1><<<ggrid, 256, 0, stream>>>(value, Wv, nullptr, Vh);

    rope_kernel<<<(2 * B_DIM * H_DIM * N_DIM * 32) / 256, 256, 0, stream>>>(Qh, Kh, qpos, kpos);

    flash_kernel<<<dim3(N_DIM / 64, B_DIM * H_DIM), 256, 0, stream>>>(Qh, Kh, Vh, Xb);

    gemm_xwT<0><<<ggrid, 256, 0, stream>>>(Xb, Wo, bo, out);
}

// Round 2
// 678.186 us; speedup vs baseline: 2.1073x; 2.1073x over previous
//
#include <hip/hip_runtime.h>
#include <hip/hip_bf16.h>

#define B_DIM 8
#define N_DIM 1024
#define C_DIM 768
#define H_DIM 12
#define HD    64
#define M_DIM (B_DIM * N_DIM)   // 8192
#define BH    (B_DIM * H_DIM)   // 96

typedef __attribute__((ext_vector_type(8))) short s16x8;
typedef __attribute__((ext_vector_type(4))) float f32x4;

__device__ __forceinline__ unsigned short f2bf(float f) {
    unsigned u = __float_as_uint(f);
    return (unsigned short)((u + 0x7FFFu + ((u >> 16) & 1u)) >> 16);
}
__device__ __forceinline__ float bf2f(unsigned short h) {
    return __uint_as_float(((unsigned)h) << 16);
}

// ---------------------------------------------------------------------------
// fp32 GEMM: Out = X @ W^T (+ bias).  (unchanged from round 0; MFMA next round)
// MODE 0: Out[m][d] = dot + bias[d]; MODE 1: head layout (B,H,n,hd)
// ---------------------------------------------------------------------------
template<int MODE>
__global__ __launch_bounds__(256)
void gemm_xwT(const float* __restrict__ X, const float* __restrict__ W,
              const float* __restrict__ bias, float* __restrict__ Out)
{
    __shared__ float As[16][68];
    __shared__ float Bs[16][68];

    const int tid = threadIdx.x;
    const int m0 = blockIdx.x * 64;
    const int n0 = blockIdx.y * 64;
    const int ty = tid >> 4, tx = tid & 15;
    const int lr = tid >> 2;
    const int lc = (tid & 3) << 2;

    float acc[4][4] = {};

    for (int k0 = 0; k0 < C_DIM; k0 += 16) {
        float4 xa = *(const float4*)(X + (size_t)(m0 + lr) * C_DIM + k0 + lc);
        float4 wa = *(const float4*)(W + (size_t)(n0 + lr) * C_DIM + k0 + lc);
        As[lc+0][lr] = xa.x; As[lc+1][lr] = xa.y; As[lc+2][lr] = xa.z; As[lc+3][lr] = xa.w;
        Bs[lc+0][lr] = wa.x; Bs[lc+1][lr] = wa.y; Bs[lc+2][lr] = wa.z; Bs[lc+3][lr] = wa.w;
        __syncthreads();
        #pragma unroll
        for (int k = 0; k < 16; ++k) {
            float4 a4 = *(const float4*)&As[k][ty * 4];
            float4 b4 = *(const float4*)&Bs[k][tx * 4];
            float av[4] = {a4.x, a4.y, a4.z, a4.w};
            float bv[4] = {b4.x, b4.y, b4.z, b4.w};
            #pragma unroll
            for (int i = 0; i < 4; ++i)
                #pragma unroll
                for (int j = 0; j < 4; ++j)
                    acc[i][j] = fmaf(av[i], bv[j], acc[i][j]);
        }
        __syncthreads();
    }

    if (MODE == 0) {
        #pragma unroll
        for (int i = 0; i < 4; ++i) {
            int m = m0 + ty * 4 + i;
            float4 o;
            o.x = acc[i][0] + bias[n0 + tx*4 + 0];
            o.y = acc[i][1] + bias[n0 + tx*4 + 1];
            o.z = acc[i][2] + bias[n0 + tx*4 + 2];
            o.w = acc[i][3] + bias[n0 + tx*4 + 3];
            *(float4*)(Out + (size_t)m * C_DIM + n0 + tx * 4) = o;
        }
    } else {
        const int h = blockIdx.y;
        #pragma unroll
        for (int i = 0; i < 4; ++i) {
            int m = m0 + ty * 4 + i;
            int b = m >> 10, n = m & 1023;
            float4 o = make_float4(acc[i][0], acc[i][1], acc[i][2], acc[i][3]);
            *(float4*)(Out + ((size_t)(b * H_DIM + h) * N_DIM + n) * HD + tx * 4) = o;
        }
    }
}

// ---------------------------------------------------------------------------
// cos/sin table: only 32 pos values x 16 freqs = 512 distinct angles.
// tab[pos*16 + j] = (cos, sin) of pos * 100^(-j/16)
// ---------------------------------------------------------------------------
__global__ void angles512(float2* __restrict__ tab)
{
    int t = threadIdx.x;            // 512 threads, 1 block
    int pos = t >> 4, j = t & 15;
    float ang = (float)pos * exp2f(-(float)j * 0.41524101186092029f);
    float s, c;
    sincosf(ang, &s, &c);
    tab[t] = make_float2(c, s);
}

// ---------------------------------------------------------------------------
// Fused RoPE-2D + hi/lo bf16 split for Q (scaled by 0.125) and K.
// 32 threads per (b,h,n) row; thread handles pair (j, j+16) in 32-block blk.
// ---------------------------------------------------------------------------
__global__ __launch_bounds__(256)
void ropesplit(const float* __restrict__ Qf, const float* __restrict__ Kf,
               const int* __restrict__ qpos, const int* __restrict__ kpos,
               unsigned short* __restrict__ Qhi, unsigned short* __restrict__ Qlo,
               unsigned short* __restrict__ Khi, unsigned short* __restrict__ Klo,
               const float2* __restrict__ tab)
{
    const int ROWS = BH * N_DIM;    // 98304 rows per tensor
    int gid = blockIdx.x * 256 + threadIdx.x;
    int t = gid & 31;
    int row = gid >> 5;
    const float* src; const int* P; unsigned short *Hi, *Lo; float scale;
    if (row >= ROWS) { row -= ROWS; src = Kf; P = kpos; Hi = Khi; Lo = Klo; scale = 1.0f; }
    else             {              src = Qf; P = qpos; Hi = Qhi; Lo = Qlo; scale = 0.125f; }

    int j   = t & 15;
    int blk = t >> 4;
    int n   = row & (N_DIM - 1);
    int b   = row / (N_DIM * H_DIM);

    int pos = P[(b * N_DIM + n) * 2 + blk];
    float2 cs = tab[pos * 16 + j];

    size_t base = (size_t)row * HD + blk * 32;
    float x1 = src[base + j];
    float x2 = src[base + j + 16];
    float r1 = (x1 * cs.x - x2 * cs.y) * scale;
    float r2 = (x2 * cs.x + x1 * cs.y) * scale;

    unsigned short h1 = f2bf(r1);
    unsigned short l1 = f2bf(r1 - bf2f(h1));
    unsigned short h2 = f2bf(r2);
    unsigned short l2 = f2bf(r2 - bf2f(h2));
    Hi[base + j]      = h1;  Lo[base + j]      = l1;
    Hi[base + j + 16] = h2;  Lo[base + j + 16] = l2;
}

// ---------------------------------------------------------------------------
// V: (B,H,N,64) fp32 -> V^T (B,H,64,N) bf16, 64x64 LDS tile transpose
// ---------------------------------------------------------------------------
__global__ __launch_bounds__(256)
void vtrans(const float* __restrict__ Vf, unsigned short* __restrict__ Vt)
{
    __shared__ unsigned short T[64][72];
    const int bh = blockIdx.y;
    const int nt = blockIdx.x;
    const int tid = threadIdx.x;
    const size_t hb = (size_t)bh * (N_DIM * HD);

    #pragma unroll
    for (int it = 0; it < 4; ++it) {
        int f = tid + it * 256;          // 0..1023
        int r = f >> 4;                  // n-row 0..63
        int c4 = (f & 15) * 4;           // d 0..60
        float4 v = *(const float4*)(Vf + hb + (size_t)(nt * 64 + r) * HD + c4);
        T[c4 + 0][r] = f2bf(v.x);
        T[c4 + 1][r] = f2bf(v.y);
        T[c4 + 2][r] = f2bf(v.z);
        T[c4 + 3][r] = f2bf(v.w);
    }
    __syncthreads();
    #pragma unroll
    for (int it = 0; it < 2; ++it) {
        int f = tid + it * 256;          // 0..511
        int d = f >> 3;
        int nn = (f & 7) * 8;
        *(s16x8*)(Vt + hb + (size_t)d * N_DIM + nt * 64 + nn) = *(const s16x8*)&T[d][nn];
    }
}

// ---------------------------------------------------------------------------
// MFMA flash attention. Block = 4 waves, 64 Q-rows, one (b,h). 16 K-tiles.
// Swapped QK^T: St = mfma(A=K rows, B=Q rows) -> C: col=q (lane&15), row=k.
// QK 3-pass hi/lo split (error ~2^-17); PV single-pass bf16.
// x^T accumulated: col=q, row=d. P bounced through wave-private padded LDS.
// ---------------------------------------------------------------------------
__global__ __launch_bounds__(256)
void attn_mfma(const unsigned short* __restrict__ Qhi, const unsigned short* __restrict__ Qlo,
               const unsigned short* __restrict__ Khi, const unsigned short* __restrict__ Klo,
               const unsigned short* __restrict__ Vt, float* __restrict__ Xout)
{
    __shared__ short sKh[64][72];
    __shared__ short sKl[64][72];
    __shared__ short sVt[64][72];
    __shared__ short sP[4][16][72];

    const int tid  = threadIdx.x;
    const int lane = tid & 63;
    const int wv   = tid >> 6;
    const int c    = lane & 15;      // output col (q); also row-in-subtile for A-frags
    const int g    = lane >> 4;      // k-slice group

    const int bh = blockIdx.y;
    const int q0 = blockIdx.x * 64;
    const size_t hb = (size_t)bh * (N_DIM * HD);

    // Q B-fragments, kept in registers for the whole block
    const size_t qoff = hb + (size_t)(q0 + wv * 16 + c) * HD;
    s16x8 qh[2], ql[2];
    qh[0] = *(const s16x8*)(Qhi + qoff + 8 * g);
    qh[1] = *(const s16x8*)(Qhi + qoff + 32 + 8 * g);
    ql[0] = *(const s16x8*)(Qlo + qoff + 8 * g);
    ql[1] = *(const s16x8*)(Qlo + qoff + 32 + 8 * g);

    f32x4 acc[4] = {};               // x^T: d = 16*sd + 4*g + reg, q = c
    float m_st = -3.0e38f, l_st = 0.0f;

    for (int kt = 0; kt < 16; ++kt) {
        __syncthreads();
        // stage K hi/lo rows and V^T tile
        #pragma unroll
        for (int it = 0; it < 2; ++it) {
            int f = tid + it * 256;      // 0..511
            int row = f >> 3;
            int ch = (f & 7) * 8;
            size_t kg = hb + (size_t)(kt * 64 + row) * HD + ch;
            *(s16x8*)&sKh[row][ch] = *(const s16x8*)(Khi + kg);
            *(s16x8*)&sKl[row][ch] = *(const s16x8*)(Klo + kg);
            *(s16x8*)&sVt[row][ch] = *(const s16x8*)(Vt + hb + (size_t)row * N_DIM + kt * 64 + ch);
        }
        __syncthreads();

        // St = K * Q^T (3-pass): subtile st covers k rows 16st..16st+15
        f32x4 s[4] = {};
        #pragma unroll
        for (int st = 0; st < 4; ++st) {
            s16x8 a0 = *(const s16x8*)&sKh[16 * st + c][8 * g];
            s16x8 a1 = *(const s16x8*)&sKh[16 * st + c][32 + 8 * g];
            s16x8 b0 = *(const s16x8*)&sKl[16 * st + c][8 * g];
            s16x8 b1 = *(const s16x8*)&sKl[16 * st + c][32 + 8 * g];
            s[st] = __builtin_amdgcn_mfma_f32_16x16x32_bf16(a0, qh[0], s[st], 0, 0, 0);
            s[st] = __builtin_amdgcn_mfma_f32_16x16x32_bf16(a1, qh[1], s[st], 0, 0, 0);
            s[st] = __builtin_amdgcn_mfma_f32_16x16x32_bf16(a0, ql[0], s[st], 0, 0, 0);
            s[st] = __builtin_amdgcn_mfma_f32_16x16x32_bf16(a1, ql[1], s[st], 0, 0, 0);
            s[st] = __builtin_amdgcn_mfma_f32_16x16x32_bf16(b0, qh[0], s[st], 0, 0, 0);
            s[st] = __builtin_amdgcn_mfma_f32_16x16x32_bf16(b1, qh[1], s[st], 0, 0, 0);
        }

        // online softmax over k (per lane: 16 values for q=c; reduce over 4 g-lanes)
        float pm = -3.0e38f;
        #pragma unroll
        for (int st = 0; st < 4; ++st)
            #pragma unroll
            for (int r = 0; r < 4; ++r)
                pm = fmaxf(pm, s[st][r]);
        pm = fmaxf(pm, __shfl_xor(pm, 16, 64));
        pm = fmaxf(pm, __shfl_xor(pm, 32, 64));
        float mnew = fmaxf(m_st, pm);
        float alpha = __expf(m_st - mnew);
        float p[4][4];
        float rs = 0.0f;
        #pragma unroll
        for (int st = 0; st < 4; ++st)
            #pragma unroll
            for (int r = 0; r < 4; ++r) {
                p[st][r] = __expf(s[st][r] - mnew);
                rs += p[st][r];
            }
        rs += __shfl_xor(rs, 16, 64);
        rs += __shfl_xor(rs, 32, 64);
        l_st = alpha * l_st + rs;
        m_st = mnew;
        #pragma unroll
        for (int sd = 0; sd < 4; ++sd)
            acc[sd] *= alpha;

        // P -> bf16 -> wave-private LDS [q=c][k], k = 16st + 4g + r
        #pragma unroll
        for (int st = 0; st < 4; ++st) {
            unsigned w0 = (unsigned)f2bf(p[st][0]) | ((unsigned)f2bf(p[st][1]) << 16);
            unsigned w1 = (unsigned)f2bf(p[st][2]) | ((unsigned)f2bf(p[st][3]) << 16);
            *(uint2*)&sP[wv][c][16 * st + 4 * g] = make_uint2(w0, w1);
        }

        // x^T += V^T * P  (A = V^T rows d=16sd+c; B = P^T: lane reads P[q=c][k-slice])
        #pragma unroll
        for (int m = 0; m < 2; ++m) {
            s16x8 pb = *(const s16x8*)&sP[wv][c][32 * m + 8 * g];
            #pragma unroll
            for (int sd = 0; sd < 4; ++sd) {
                s16x8 va = *(const s16x8*)&sVt[16 * sd + c][32 * m + 8 * g];
                acc[sd] = __builtin_amdgcn_mfma_f32_16x16x32_bf16(va, pb, acc[sd], 0, 0, 0);
            }
        }
    }

    // normalize + write x (B,N,C): lane holds x[q=c][d=16sd+4g+reg]
    const int b = bh / H_DIM, h = bh % H_DIM;
    const int q = q0 + wv * 16 + c;
    float invl = 1.0f / l_st;
    #pragma unroll
    for (int sd = 0; sd < 4; ++sd) {
        float4 o;
        o.x = acc[sd][0] * invl;
        o.y = acc[sd][1] * invl;
        o.z = acc[sd][2] * invl;
        o.w = acc[sd][3] * invl;
        *(float4*)(Xout + ((size_t)(b * N_DIM + q)) * C_DIM + h * HD + 16 * sd + 4 * g) = o;
    }
}

// ---------------------------------------------------------------------------
extern "C" void kernel_launch(void* const* d_in, const int* in_sizes, int n_in,
                              void* d_out, int out_size, void* d_ws, size_t ws_size,
                              hipStream_t stream)
{
    const float* query = (const float*)d_in[0];
    const float* key_  = (const float*)d_in[1];
    const float* value = (const float*)d_in[2];
    const int*   qpos  = (const int*)d_in[3];
    const int*   kpos  = (const int*)d_in[4];
    const float* Wq    = (const float*)d_in[5];
    const float* Wk    = (const float*)d_in[6];
    const float* Wv    = (const float*)d_in[7];
    const float* Wo    = (const float*)d_in[8];
    const float* bo    = (const float*)d_in[9];
    float* out = (float*)d_out;

    const size_t TEN = (size_t)BH * N_DIM * HD;      // 6,291,456

    float* Qf = (float*)d_ws;                        // later aliased as Xb
    float* Kf = Qf + TEN;                            // later aliased as Vt (bf16)
    float* Vf = Kf + TEN;
    unsigned short* Qhi = (unsigned short*)(Vf + TEN);
    unsigned short* Qlo = Qhi + TEN;
    unsigned short* Khi = Qlo + TEN;
    unsigned short* Klo = Khi + TEN;
    float2* tab = (float2*)(Klo + TEN);              // 512 float2
    unsigned short* Vt = (unsigned short*)Kf;        // overlays Kf (free after ropesplit)
    float* Xb = Qf;                                  // overlays Qf (free after ropesplit)

    dim3 ggrid(M_DIM / 64, C_DIM / 64);              // 128 x 12

    angles512<<<1, 512, 0, stream>>>(tab);
    gemm_xwT<1><<<ggrid, 256, 0, stream>>>(query, Wq, nullptr, Qf);
    gemm_xwT<1><<<ggrid, 256, 0, stream>>>(key_,  Wk, nullptr, Kf);
    gemm_xwT<1><<<ggrid, 256, 0, stream>>>(value, Wv, nullptr, Vf);

    ropesplit<<<(2 * BH * N_DIM * 32) / 256, 256, 0, stream>>>(
        Qf, Kf, qpos, kpos, Qhi, Qlo, Khi, Klo, tab);

    vtrans<<<dim3(N_DIM / 64, BH), 256, 0, stream>>>(Vf, Vt);

    attn_mfma<<<dim3(N_DIM / 64, BH), 256, 0, stream>>>(Qhi, Qlo, Khi, Klo, Vt, Xb);

    gemm_xwT<0><<<ggrid, 256, 0, stream>>>(Xb, Wo, bo, out);
}

// Round 3
// 548.608 us; speedup vs baseline: 2.6051x; 1.2362x over previous
//
#include <hip/hip_runtime.h>
#include <hip/hip_bf16.h>

#define B_DIM 8
#define N_DIM 1024
#define C_DIM 768
#define H_DIM 12
#define HD    64
#define M_DIM (B_DIM * N_DIM)   // 8192
#define BH    (B_DIM * H_DIM)   // 96

typedef __attribute__((ext_vector_type(8))) short s16x8;
typedef __attribute__((ext_vector_type(4))) float f32x4;

__device__ __forceinline__ unsigned short f2bf(float f) {
    unsigned u = __float_as_uint(f);
    return (unsigned short)((u + 0x7FFFu + ((u >> 16) & 1u)) >> 16);
}
__device__ __forceinline__ float bf2f(unsigned short h) {
    return __uint_as_float(((unsigned)h) << 16);
}

// ---------------------------------------------------------------------------
// hi/lo bf16 split: x = bf(x) + bf(x - bf(x)), 8 elems/thread
// ---------------------------------------------------------------------------
__global__ __launch_bounds__(256)
void split_hl(const float* __restrict__ src, unsigned short* __restrict__ hi,
              unsigned short* __restrict__ lo, int n8)
{
    int i = blockIdx.x * 256 + threadIdx.x;
    if (i >= n8) return;
    float4 v0 = *(const float4*)(src + (size_t)i * 8);
    float4 v1 = *(const float4*)(src + (size_t)i * 8 + 4);
    float f[8] = {v0.x, v0.y, v0.z, v0.w, v1.x, v1.y, v1.z, v1.w};
    s16x8 h, l;
    #pragma unroll
    for (int j = 0; j < 8; ++j) {
        unsigned short hh = f2bf(f[j]);
        h[j] = (short)hh;
        l[j] = (short)f2bf(f[j] - bf2f(hh));
    }
    *(s16x8*)(hi + (size_t)i * 8) = h;
    *(s16x8*)(lo + (size_t)i * 8) = l;
}

// ---------------------------------------------------------------------------
// MFMA GEMM, 3-pass hi/lo folded into K' = 3*768 = 2304.
// out[m][d] = sum X[m]·W[d]  (A = X rows, B = W rows)
// kb 0..23: Ah*Bh   24..47: Al*Bh   48..71: Ah*Bl
// BM=128, BN=64, BK=32; 4 waves (2x2), wave tile 64x32, acc[4][2].
// MODE 0: fp32 Out[m][768] + bias ; MODE 1: fp32 head layout (B,H,n,hd)
// ---------------------------------------------------------------------------
template<int MODE>
__global__ __launch_bounds__(256)
void gemm_mfma(const unsigned short* __restrict__ Ah, const unsigned short* __restrict__ Al,
               const unsigned short* __restrict__ Bh, const unsigned short* __restrict__ Bl,
               const float* __restrict__ bias, float* __restrict__ Out)
{
    __shared__ unsigned short sA[2][4][128][8];   // [buf][kslice][m][8]
    __shared__ unsigned short sB[2][4][64][8];    // [buf][kslice][d][8]

    const int tid  = threadIdx.x;
    const int lane = tid & 63;
    const int w    = tid >> 6;
    const int wr   = w >> 1, wc = w & 1;
    const int c    = lane & 15, g = lane >> 4;
    const int m0   = blockIdx.x * 128;
    const int n0   = blockIdx.y * 64;

    f32x4 acc[4][2] = {};

    auto stage = [&](int kb, int buf) {
        int p = kb >= 48 ? 2 : (kb >= 24 ? 1 : 0);
        const unsigned short* Ap = (p == 1) ? Al : Ah;
        const unsigned short* Bp = (p == 2) ? Bl : Bh;
        int ks = (kb - p * 24) * 32;
        #pragma unroll
        for (int t = 0; t < 3; ++t) {
            int is = w * 3 + t;                      // wave-uniform
            if (is < 8) {                            // A issues 0..7
                int gg = is & 3, half = is >> 2;
                const unsigned short* srcp =
                    Ap + (size_t)(m0 + half * 64 + lane) * C_DIM + ks + 8 * gg;
                __builtin_amdgcn_global_load_lds(
                    (const __attribute__((address_space(1))) void*)srcp,
                    (__attribute__((address_space(3))) void*)&sA[buf][gg][half * 64][0],
                    16, 0, 0);
            } else {                                 // B issues 8..11
                int gg = is - 8;
                const unsigned short* srcp =
                    Bp + (size_t)(n0 + lane) * C_DIM + ks + 8 * gg;
                __builtin_amdgcn_global_load_lds(
                    (const __attribute__((address_space(1))) void*)srcp,
                    (__attribute__((address_space(3))) void*)&sB[buf][gg][0][0],
                    16, 0, 0);
            }
        }
    };

    stage(0, 0);
    __syncthreads();

    for (int kb = 0; kb < 72; ++kb) {
        int buf = kb & 1;
        if (kb < 71) stage(kb + 1, buf ^ 1);
        s16x8 a[4], b[2];
        #pragma unroll
        for (int mi = 0; mi < 4; ++mi)
            a[mi] = *(const s16x8*)&sA[buf][g][wr * 64 + 16 * mi + c][0];
        #pragma unroll
        for (int ni = 0; ni < 2; ++ni)
            b[ni] = *(const s16x8*)&sB[buf][g][wc * 32 + 16 * ni + c][0];
        #pragma unroll
        for (int mi = 0; mi < 4; ++mi)
            #pragma unroll
            for (int ni = 0; ni < 2; ++ni)
                acc[mi][ni] = __builtin_amdgcn_mfma_f32_16x16x32_bf16(a[mi], b[ni], acc[mi][ni], 0, 0, 0);
        __syncthreads();
    }

    if (MODE == 0) {
        #pragma unroll
        for (int ni = 0; ni < 2; ++ni) {
            int d = n0 + wc * 32 + 16 * ni + c;
            float bv = bias[d];
            #pragma unroll
            for (int mi = 0; mi < 4; ++mi)
                #pragma unroll
                for (int r = 0; r < 4; ++r) {
                    int m = m0 + wr * 64 + 16 * mi + 4 * g + r;
                    Out[(size_t)m * C_DIM + d] = acc[mi][ni][r] + bv;
                }
        }
    } else {
        const int h = blockIdx.y;
        #pragma unroll
        for (int ni = 0; ni < 2; ++ni) {
            int dh = wc * 32 + 16 * ni + c;
            #pragma unroll
            for (int mi = 0; mi < 4; ++mi)
                #pragma unroll
                for (int r = 0; r < 4; ++r) {
                    int m = m0 + wr * 64 + 16 * mi + 4 * g + r;
                    int b_ = m >> 10, n = m & 1023;
                    Out[((size_t)(b_ * H_DIM + h) * N_DIM + n) * HD + dh] = acc[mi][ni][r];
                }
        }
    }
}

// ---------------------------------------------------------------------------
// cos/sin table: 32 pos x 16 freqs
// ---------------------------------------------------------------------------
__global__ void angles512(float2* __restrict__ tab)
{
    int t = threadIdx.x;
    int pos = t >> 4, j = t & 15;
    float ang = (float)pos * exp2f(-(float)j * 0.41524101186092029f);
    float s, c;
    sincosf(ang, &s, &c);
    tab[t] = make_float2(c, s);
}

// ---------------------------------------------------------------------------
// Fused RoPE-2D + hi/lo bf16 split for Q (scaled 0.125) and K
// ---------------------------------------------------------------------------
__global__ __launch_bounds__(256)
void ropesplit(const float* __restrict__ Qf, const float* __restrict__ Kf,
               const int* __restrict__ qpos, const int* __restrict__ kpos,
               unsigned short* __restrict__ Qhi, unsigned short* __restrict__ Qlo,
               unsigned short* __restrict__ Khi, unsigned short* __restrict__ Klo,
               const float2* __restrict__ tab)
{
    const int ROWS = BH * N_DIM;
    int gid = blockIdx.x * 256 + threadIdx.x;
    int t = gid & 31;
    int row = gid >> 5;
    const float* src; const int* P; unsigned short *Hi, *Lo; float scale;
    if (row >= ROWS) { row -= ROWS; src = Kf; P = kpos; Hi = Khi; Lo = Klo; scale = 1.0f; }
    else             {              src = Qf; P = qpos; Hi = Qhi; Lo = Qlo; scale = 0.125f; }

    int j   = t & 15;
    int blk = t >> 4;
    int n   = row & (N_DIM - 1);
    int b   = row / (N_DIM * H_DIM);

    int pos = P[(b * N_DIM + n) * 2 + blk];
    float2 cs = tab[pos * 16 + j];

    size_t base = (size_t)row * HD + blk * 32;
    float x1 = src[base + j];
    float x2 = src[base + j + 16];
    float r1 = (x1 * cs.x - x2 * cs.y) * scale;
    float r2 = (x2 * cs.x + x1 * cs.y) * scale;

    unsigned short h1 = f2bf(r1);
    unsigned short l1 = f2bf(r1 - bf2f(h1));
    unsigned short h2 = f2bf(r2);
    unsigned short l2 = f2bf(r2 - bf2f(h2));
    Hi[base + j]      = h1;  Lo[base + j]      = l1;
    Hi[base + j + 16] = h2;  Lo[base + j + 16] = l2;
}

// ---------------------------------------------------------------------------
// V: (B,H,N,64) fp32 -> V^T (B,H,64,N) bf16
// ---------------------------------------------------------------------------
__global__ __launch_bounds__(256)
void vtrans(const float* __restrict__ Vf, unsigned short* __restrict__ Vt)
{
    __shared__ unsigned short T[64][72];
    const int bh = blockIdx.y;
    const int nt = blockIdx.x;
    const int tid = threadIdx.x;
    const size_t hb = (size_t)bh * (N_DIM * HD);

    #pragma unroll
    for (int it = 0; it < 4; ++it) {
        int f = tid + it * 256;
        int r = f >> 4;
        int c4 = (f & 15) * 4;
        float4 v = *(const float4*)(Vf + hb + (size_t)(nt * 64 + r) * HD + c4);
        T[c4 + 0][r] = f2bf(v.x);
        T[c4 + 1][r] = f2bf(v.y);
        T[c4 + 2][r] = f2bf(v.z);
        T[c4 + 3][r] = f2bf(v.w);
    }
    __syncthreads();
    #pragma unroll
    for (int it = 0; it < 2; ++it) {
        int f = tid + it * 256;
        int d = f >> 3;
        int nn = (f & 7) * 8;
        *(s16x8*)(Vt + hb + (size_t)d * N_DIM + nt * 64 + nn) = *(const s16x8*)&T[d][nn];
    }
}

// ---------------------------------------------------------------------------
// MFMA flash attention (as round 1), now emitting hi/lo bf16 x for the O-GEMM
// ---------------------------------------------------------------------------
__global__ __launch_bounds__(256)
void attn_mfma(const unsigned short* __restrict__ Qhi, const unsigned short* __restrict__ Qlo,
               const unsigned short* __restrict__ Khi, const unsigned short* __restrict__ Klo,
               const unsigned short* __restrict__ Vt,
               unsigned short* __restrict__ Xbh, unsigned short* __restrict__ Xbl)
{
    __shared__ short sKh[64][72];
    __shared__ short sKl[64][72];
    __shared__ short sVt[64][72];
    __shared__ short sP[4][16][72];

    const int tid  = threadIdx.x;
    const int lane = tid & 63;
    const int wv   = tid >> 6;
    const int c    = lane & 15;
    const int g    = lane >> 4;

    const int bh = blockIdx.y;
    const int q0 = blockIdx.x * 64;
    const size_t hb = (size_t)bh * (N_DIM * HD);

    const size_t qoff = hb + (size_t)(q0 + wv * 16 + c) * HD;
    s16x8 qh[2], ql[2];
    qh[0] = *(const s16x8*)(Qhi + qoff + 8 * g);
    qh[1] = *(const s16x8*)(Qhi + qoff + 32 + 8 * g);
    ql[0] = *(const s16x8*)(Qlo + qoff + 8 * g);
    ql[1] = *(const s16x8*)(Qlo + qoff + 32 + 8 * g);

    f32x4 acc[4] = {};
    float m_st = -3.0e38f, l_st = 0.0f;

    for (int kt = 0; kt < 16; ++kt) {
        __syncthreads();
        #pragma unroll
        for (int it = 0; it < 2; ++it) {
            int f = tid + it * 256;
            int row = f >> 3;
            int ch = (f & 7) * 8;
            size_t kg = hb + (size_t)(kt * 64 + row) * HD + ch;
            *(s16x8*)&sKh[row][ch] = *(const s16x8*)(Khi + kg);
            *(s16x8*)&sKl[row][ch] = *(const s16x8*)(Klo + kg);
            *(s16x8*)&sVt[row][ch] = *(const s16x8*)(Vt + hb + (size_t)row * N_DIM + kt * 64 + ch);
        }
        __syncthreads();

        f32x4 s[4] = {};
        #pragma unroll
        for (int st = 0; st < 4; ++st) {
            s16x8 a0 = *(const s16x8*)&sKh[16 * st + c][8 * g];
            s16x8 a1 = *(const s16x8*)&sKh[16 * st + c][32 + 8 * g];
            s16x8 b0 = *(const s16x8*)&sKl[16 * st + c][8 * g];
            s16x8 b1 = *(const s16x8*)&sKl[16 * st + c][32 + 8 * g];
            s[st] = __builtin_amdgcn_mfma_f32_16x16x32_bf16(a0, qh[0], s[st], 0, 0, 0);
            s[st] = __builtin_amdgcn_mfma_f32_16x16x32_bf16(a1, qh[1], s[st], 0, 0, 0);
            s[st] = __builtin_amdgcn_mfma_f32_16x16x32_bf16(a0, ql[0], s[st], 0, 0, 0);
            s[st] = __builtin_amdgcn_mfma_f32_16x16x32_bf16(a1, ql[1], s[st], 0, 0, 0);
            s[st] = __builtin_amdgcn_mfma_f32_16x16x32_bf16(b0, qh[0], s[st], 0, 0, 0);
            s[st] = __builtin_amdgcn_mfma_f32_16x16x32_bf16(b1, qh[1], s[st], 0, 0, 0);
        }

        float pm = -3.0e38f;
        #pragma unroll
        for (int st = 0; st < 4; ++st)
            #pragma unroll
            for (int r = 0; r < 4; ++r)
                pm = fmaxf(pm, s[st][r]);
        pm = fmaxf(pm, __shfl_xor(pm, 16, 64));
        pm = fmaxf(pm, __shfl_xor(pm, 32, 64));
        float mnew = fmaxf(m_st, pm);
        float alpha = __expf(m_st - mnew);
        float p[4][4];
        float rs = 0.0f;
        #pragma unroll
        for (int st = 0; st < 4; ++st)
            #pragma unroll
            for (int r = 0; r < 4; ++r) {
                p[st][r] = __expf(s[st][r] - mnew);
                rs += p[st][r];
            }
        rs += __shfl_xor(rs, 16, 64);
        rs += __shfl_xor(rs, 32, 64);
        l_st = alpha * l_st + rs;
        m_st = mnew;
        #pragma unroll
        for (int sd = 0; sd < 4; ++sd)
            acc[sd] *= alpha;

        #pragma unroll
        for (int st = 0; st < 4; ++st) {
            unsigned w0 = (unsigned)f2bf(p[st][0]) | ((unsigned)f2bf(p[st][1]) << 16);
            unsigned w1 = (unsigned)f2bf(p[st][2]) | ((unsigned)f2bf(p[st][3]) << 16);
            *(uint2*)&sP[wv][c][16 * st + 4 * g] = make_uint2(w0, w1);
        }

        #pragma unroll
        for (int m = 0; m < 2; ++m) {
            s16x8 pb = *(const s16x8*)&sP[wv][c][32 * m + 8 * g];
            #pragma unroll
            for (int sd = 0; sd < 4; ++sd) {
                s16x8 va = *(const s16x8*)&sVt[16 * sd + c][32 * m + 8 * g];
                acc[sd] = __builtin_amdgcn_mfma_f32_16x16x32_bf16(va, pb, acc[sd], 0, 0, 0);
            }
        }
    }

    const int b = bh / H_DIM, h = bh % H_DIM;
    const int q = q0 + wv * 16 + c;
    float invl = 1.0f / l_st;
    size_t obase = ((size_t)(b * N_DIM + q)) * C_DIM + h * HD;
    #pragma unroll
    for (int sd = 0; sd < 4; ++sd) {
        unsigned short hs[4], ls[4];
        #pragma unroll
        for (int r = 0; r < 4; ++r) {
            float o = acc[sd][r] * invl;
            hs[r] = f2bf(o);
            ls[r] = f2bf(o - bf2f(hs[r]));
        }
        *(uint2*)(Xbh + obase + 16 * sd + 4 * g) =
            make_uint2((unsigned)hs[0] | ((unsigned)hs[1] << 16),
                       (unsigned)hs[2] | ((unsigned)hs[3] << 16));
        *(uint2*)(Xbl + obase + 16 * sd + 4 * g) =
            make_uint2((unsigned)ls[0] | ((unsigned)ls[1] << 16),
                       (unsigned)ls[2] | ((unsigned)ls[3] << 16));
    }
}

// ---------------------------------------------------------------------------
extern "C" void kernel_launch(void* const* d_in, const int* in_sizes, int n_in,
                              void* d_out, int out_size, void* d_ws, size_t ws_size,
                              hipStream_t stream)
{
    const float* query = (const float*)d_in[0];
    const float* key_  = (const float*)d_in[1];
    const float* value = (const float*)d_in[2];
    const int*   qpos  = (const int*)d_in[3];
    const int*   kpos  = (const int*)d_in[4];
    const float* Wq    = (const float*)d_in[5];
    const float* Wk    = (const float*)d_in[6];
    const float* Wv    = (const float*)d_in[7];
    const float* Wo    = (const float*)d_in[8];
    const float* bo    = (const float*)d_in[9];
    float* out = (float*)d_out;

    const size_t TEN = (size_t)BH * N_DIM * HD;          // 6,291,456
    const size_t WN  = (size_t)C_DIM * C_DIM;            // 589,824

    float* wsf = (float*)d_ws;
    unsigned short* XS = (unsigned short*)d_ws;          // 6 x TEN ushort slots
    unsigned short* WS = (unsigned short*)(wsf + 3 * TEN); // 8 x WN ushort slots
    float* Qf = wsf + 3 * TEN + 4 * WN;
    float* Kf = Qf + TEN;
    float* Vf = Kf + TEN;
    float2* tab = (float2*)(Vf + TEN);                   // 512 float2

    // overlays (stream-ordered; regions dead by the time they're reused)
    unsigned short* Qhi = XS + 0 * TEN;
    unsigned short* Qlo = XS + 1 * TEN;
    unsigned short* Khi = XS + 2 * TEN;
    unsigned short* Klo = XS + 3 * TEN;
    unsigned short* Vt  = XS + 4 * TEN;
    unsigned short* Xbh = XS + 5 * TEN;
    unsigned short* Xbl = (unsigned short*)Kf;

    const int n8X = (int)(TEN / 8), n8W = (int)(WN / 8);

    angles512<<<1, 512, 0, stream>>>(tab);

    split_hl<<<(n8X + 255) / 256, 256, 0, stream>>>(query, XS + 0 * TEN, XS + 1 * TEN, n8X);
    split_hl<<<(n8X + 255) / 256, 256, 0, stream>>>(key_,  XS + 2 * TEN, XS + 3 * TEN, n8X);
    split_hl<<<(n8X + 255) / 256, 256, 0, stream>>>(value, XS + 4 * TEN, XS + 5 * TEN, n8X);
    split_hl<<<(n8W + 255) / 256, 256, 0, stream>>>(Wq, WS + 0 * WN, WS + 1 * WN, n8W);
    split_hl<<<(n8W + 255) / 256, 256, 0, stream>>>(Wk, WS + 2 * WN, WS + 3 * WN, n8W);
    split_hl<<<(n8W + 255) / 256, 256, 0, stream>>>(Wv, WS + 4 * WN, WS + 5 * WN, n8W);
    split_hl<<<(n8W + 255) / 256, 256, 0, stream>>>(Wo, WS + 6 * WN, WS + 7 * WN, n8W);

    dim3 ggrid(M_DIM / 128, C_DIM / 64);                 // 64 x 12
    gemm_mfma<1><<<ggrid, 256, 0, stream>>>(XS + 0 * TEN, XS + 1 * TEN,
                                            WS + 0 * WN, WS + 1 * WN, nullptr, Qf);
    gemm_mfma<1><<<ggrid, 256, 0, stream>>>(XS + 2 * TEN, XS + 3 * TEN,
                                            WS + 2 * WN, WS + 3 * WN, nullptr, Kf);
    gemm_mfma<1><<<ggrid, 256, 0, stream>>>(XS + 4 * TEN, XS + 5 * TEN,
                                            WS + 4 * WN, WS + 5 * WN, nullptr, Vf);

    ropesplit<<<(2 * BH * N_DIM * 32) / 256, 256, 0, stream>>>(
        Qf, Kf, qpos, kpos, Qhi, Qlo, Khi, Klo, tab);

    vtrans<<<dim3(N_DIM / 64, BH), 256, 0, stream>>>(Vf, Vt);

    attn_mfma<<<dim3(N_DIM / 64, BH), 256, 0, stream>>>(Qhi, Qlo, Khi, Klo, Vt, Xbh, Xbl);

    gemm_mfma<0><<<ggrid, 256, 0, stream>>>(Xbh, Xbl, WS + 6 * WN, WS + 7 * WN, bo, out);
}

// Round 4
// 431.734 us; speedup vs baseline: 3.3103x; 1.2707x over previous
//
#include <hip/hip_runtime.h>
#include <hip/hip_bf16.h>
#include <hip/hip_fp16.h>

#define B_DIM 8
#define N_DIM 1024
#define C_DIM 768
#define H_DIM 12
#define HD    64
#define M_DIM (B_DIM * N_DIM)   // 8192
#define BH    (B_DIM * H_DIM)   // 96

static constexpr size_t TEN = (size_t)M_DIM * C_DIM;     // 6,291,456
static constexpr size_t WN  = (size_t)C_DIM * C_DIM;     // 589,824

typedef __attribute__((ext_vector_type(8))) short    s16x8;
typedef __attribute__((ext_vector_type(8))) _Float16 f16x8;
typedef __attribute__((ext_vector_type(4))) float    f32x4;

__device__ __forceinline__ unsigned short f2bf(float f) {
    unsigned u = __float_as_uint(f);
    return (unsigned short)((u + 0x7FFFu + ((u >> 16) & 1u)) >> 16);
}
__device__ __forceinline__ float bf2f(unsigned short h) {
    return __uint_as_float(((unsigned)h) << 16);
}
__device__ __forceinline__ unsigned short f2h(float f) {
    __half h = __float2half(f);          // RTN
    return __half_as_ushort(h);
}

// ---------------------------------------------------------------------------
// bf16 hi/lo splits (inputs for the 3-pass GEMMs)
// ---------------------------------------------------------------------------
__global__ __launch_bounds__(256)
void splitX(const float* __restrict__ q, const float* __restrict__ k,
            const float* __restrict__ v, unsigned short* __restrict__ XS)
{
    int t = blockIdx.y;
    const float* src = (t == 0) ? q : (t == 1 ? k : v);
    unsigned short* hi = XS + (size_t)(2 * t) * TEN;
    unsigned short* lo = hi + TEN;
    size_t i = (size_t)blockIdx.x * 256 + threadIdx.x;   // < TEN/8
    float4 v0 = *(const float4*)(src + i * 8);
    float4 v1 = *(const float4*)(src + i * 8 + 4);
    float f[8] = {v0.x, v0.y, v0.z, v0.w, v1.x, v1.y, v1.z, v1.w};
    s16x8 h, l;
    #pragma unroll
    for (int j = 0; j < 8; ++j) {
        unsigned short hh = f2bf(f[j]);
        h[j] = (short)hh;
        l[j] = (short)f2bf(f[j] - bf2f(hh));
    }
    *(s16x8*)(hi + i * 8) = h;
    *(s16x8*)(lo + i * 8) = l;
}

__global__ __launch_bounds__(256)
void splitW(const float* __restrict__ wq, const float* __restrict__ wk,
            const float* __restrict__ wv, const float* __restrict__ wo,
            unsigned short* __restrict__ WS)
{
    int t = blockIdx.y;
    const float* src = (t == 0) ? wq : (t == 1 ? wk : (t == 2 ? wv : wo));
    unsigned short* hi = WS + (size_t)(2 * t) * WN;
    unsigned short* lo = hi + WN;
    size_t i = (size_t)blockIdx.x * 256 + threadIdx.x;   // < WN/8
    float4 v0 = *(const float4*)(src + i * 8);
    float4 v1 = *(const float4*)(src + i * 8 + 4);
    float f[8] = {v0.x, v0.y, v0.z, v0.w, v1.x, v1.y, v1.z, v1.w};
    s16x8 h, l;
    #pragma unroll
    for (int j = 0; j < 8; ++j) {
        unsigned short hh = f2bf(f[j]);
        h[j] = (short)hh;
        l[j] = (short)f2bf(f[j] - bf2f(hh));
    }
    *(s16x8*)(hi + i * 8) = h;
    *(s16x8*)(lo + i * 8) = l;
}

// ---------------------------------------------------------------------------
// cos/sin table: 32 pos x 16 freqs
// ---------------------------------------------------------------------------
__global__ void angles512(float2* __restrict__ tab)
{
    int t = threadIdx.x;
    int pos = t >> 4, j = t & 15;
    float ang = (float)pos * exp2f(-(float)j * 0.41524101186092029f);
    float s, c;
    sincosf(ang, &s, &c);
    tab[t] = make_float2(c, s);
}

// ---------------------------------------------------------------------------
// 3-pass hi/lo bf16 MFMA GEMM, BM=128 BN=128 BK=32, 4 waves (2x2), acc[4][4].
// K' = 3*768: kb 0..23 Ah*Bh, 24..47 Al*Bh, 48..71 Ah*Bl.
// MODE 1 (QKV, z=0..2):
//   z=0/1: fused RoPE -> fp16 head layout (B,H,n,64); q scaled 0.125
//   z=2  : fp16 (B,N,C)
// MODE 0 (O-proj, z=0): fp32 (B,N,C) + bias -> Of
// ---------------------------------------------------------------------------
template<int MODE>
__global__ __launch_bounds__(256)
void gemm3(const unsigned short* __restrict__ AhQ, const unsigned short* __restrict__ AlQ,
           const unsigned short* __restrict__ AhK, const unsigned short* __restrict__ AlK,
           const unsigned short* __restrict__ AhV, const unsigned short* __restrict__ AlV,
           const unsigned short* __restrict__ WhQ, const unsigned short* __restrict__ WlQ,
           const unsigned short* __restrict__ WhK, const unsigned short* __restrict__ WlK,
           const unsigned short* __restrict__ WhV, const unsigned short* __restrict__ WlV,
           const int* __restrict__ qpos, const int* __restrict__ kpos,
           const float2* __restrict__ tab,
           unsigned short* __restrict__ OQ, unsigned short* __restrict__ OK_,
           unsigned short* __restrict__ OV,
           const float* __restrict__ bias, float* __restrict__ Of)
{
    __shared__ unsigned short sA[2][4][128][8];   // [buf][kslice][m][8]
    __shared__ unsigned short sB[2][4][128][8];   // [buf][kslice][d][8]

    const int tid  = threadIdx.x;
    const int lane = tid & 63;
    const int w    = tid >> 6;
    const int wr   = w >> 1, wc = w & 1;
    const int c    = lane & 15, g = lane >> 4;
    const int m0   = blockIdx.x * 128;
    const int n0   = blockIdx.y * 128;
    const int z    = blockIdx.z;

    const unsigned short *Ah, *Al, *Bh, *Bl;
    if (MODE == 0 || z == 0) { Ah = AhQ; Al = AlQ; Bh = WhQ; Bl = WlQ; }
    else if (z == 1)         { Ah = AhK; Al = AlK; Bh = WhK; Bl = WlK; }
    else                     { Ah = AhV; Al = AlV; Bh = WhV; Bl = WlV; }

    f32x4 acc[4][4] = {};

    auto stage = [&](int kb, int buf) {
        int p = kb >= 48 ? 2 : (kb >= 24 ? 1 : 0);
        const unsigned short* Ap = (p == 1) ? Al : Ah;
        const unsigned short* Bp = (p == 2) ? Bl : Bh;
        int ks = (kb - p * 24) * 32;
        #pragma unroll
        for (int t = 0; t < 4; ++t) {
            int is = w * 4 + t;                      // wave-uniform
            if (is < 8) {                            // A: 8 issues
                int gg = is & 3, half = is >> 2;
                const unsigned short* srcp =
                    Ap + (size_t)(m0 + half * 64 + lane) * C_DIM + ks + 8 * gg;
                __builtin_amdgcn_global_load_lds(
                    (const __attribute__((address_space(1))) void*)srcp,
                    (__attribute__((address_space(3))) void*)&sA[buf][gg][half * 64][0],
                    16, 0, 0);
            } else {                                 // B: 8 issues
                int j = is - 8, gg = j & 3, half = j >> 2;
                const unsigned short* srcp =
                    Bp + (size_t)(n0 + half * 64 + lane) * C_DIM + ks + 8 * gg;
                __builtin_amdgcn_global_load_lds(
                    (const __attribute__((address_space(1))) void*)srcp,
                    (__attribute__((address_space(3))) void*)&sB[buf][gg][half * 64][0],
                    16, 0, 0);
            }
        }
    };

    stage(0, 0);
    __syncthreads();

    for (int kb = 0; kb < 72; ++kb) {
        int buf = kb & 1;
        if (kb < 71) stage(kb + 1, buf ^ 1);
        s16x8 a[4], b[4];
        #pragma unroll
        for (int mi = 0; mi < 4; ++mi)
            a[mi] = *(const s16x8*)&sA[buf][g][wr * 64 + 16 * mi + c][0];
        #pragma unroll
        for (int ni = 0; ni < 4; ++ni)
            b[ni] = *(const s16x8*)&sB[buf][g][wc * 64 + 16 * ni + c][0];
        __builtin_amdgcn_s_setprio(1);
        #pragma unroll
        for (int mi = 0; mi < 4; ++mi)
            #pragma unroll
            for (int ni = 0; ni < 4; ++ni)
                acc[mi][ni] = __builtin_amdgcn_mfma_f32_16x16x32_bf16(a[mi], b[ni], acc[mi][ni], 0, 0, 0);
        __builtin_amdgcn_s_setprio(0);
        __syncthreads();
    }

    if (MODE == 0) {
        #pragma unroll
        for (int ni = 0; ni < 4; ++ni) {
            int d = n0 + wc * 64 + 16 * ni + c;
            float bv = bias[d];
            #pragma unroll
            for (int mi = 0; mi < 4; ++mi)
                #pragma unroll
                for (int r = 0; r < 4; ++r) {
                    int m = m0 + wr * 64 + 16 * mi + 4 * g + r;
                    Of[(size_t)m * C_DIM + d] = acc[mi][ni][r] + bv;
                }
        }
    } else if (z == 2) {
        // V -> fp16 (B,N,C)
        #pragma unroll
        for (int ni = 0; ni < 4; ++ni) {
            int d = n0 + wc * 64 + 16 * ni + c;
            #pragma unroll
            for (int mi = 0; mi < 4; ++mi)
                #pragma unroll
                for (int r = 0; r < 4; ++r) {
                    int m = m0 + wr * 64 + 16 * mi + 4 * g + r;
                    OV[(size_t)m * C_DIM + d] = f2h(acc[mi][ni][r]);
                }
        }
    } else {
        // Q/K: fused RoPE -> fp16 head layout; wave owns one full head (64 d)
        const int* P = z ? kpos : qpos;
        unsigned short* T = z ? OK_ : OQ;
        const float scale = z ? 1.0f : 0.125f;
        const int hh = (n0 >> 6) + wc;
        #pragma unroll
        for (int mi = 0; mi < 4; ++mi)
            #pragma unroll
            for (int r = 0; r < 4; ++r) {
                int m = m0 + wr * 64 + 16 * mi + 4 * g + r;
                int b = m >> 10, n = m & 1023;
                size_t base = ((size_t)(b * H_DIM + hh) * N_DIM + n) * HD;
                #pragma unroll
                for (int bb = 0; bb < 2; ++bb) {
                    int pos = P[2 * m + bb];
                    float2 cs = tab[pos * 16 + c];
                    float x1 = acc[mi][bb * 2 + 0][r];
                    float x2 = acc[mi][bb * 2 + 1][r];
                    float r1 = (x1 * cs.x - x2 * cs.y) * scale;
                    float r2 = (x2 * cs.x + x1 * cs.y) * scale;
                    T[base + bb * 32 + c]      = f2h(r1);
                    T[base + bb * 32 + 16 + c] = f2h(r2);
                }
            }
    }
}

// ---------------------------------------------------------------------------
// V: (B,N,C) fp16 -> V^T (B,H,64,N) fp16
// ---------------------------------------------------------------------------
__global__ __launch_bounds__(256)
void vtrans(const unsigned short* __restrict__ Vf, unsigned short* __restrict__ Vt)
{
    __shared__ unsigned short T[64][72];
    const int bh = blockIdx.y;
    const int nt = blockIdx.x;
    const int tid = threadIdx.x;
    const int b = bh / H_DIM, h = bh % H_DIM;
    const size_t hb = (size_t)bh * (N_DIM * HD);

    #pragma unroll
    for (int it = 0; it < 2; ++it) {
        int f = tid + it * 256;          // 0..511
        int r = f >> 3;                  // n-row 0..63
        int c8 = (f & 7) * 8;            // d 0..56
        s16x8 v = *(const s16x8*)(Vf + ((size_t)(b * N_DIM + nt * 64 + r)) * C_DIM + h * HD + c8);
        #pragma unroll
        for (int j = 0; j < 8; ++j)
            T[c8 + j][r] = (unsigned short)v[j];
    }
    __syncthreads();
    #pragma unroll
    for (int it = 0; it < 2; ++it) {
        int f = tid + it * 256;
        int d = f >> 3;
        int nn = (f & 7) * 8;
        *(s16x8*)(Vt + hb + (size_t)d * N_DIM + nt * 64 + nn) = *(const s16x8*)&T[d][nn];
    }
}

// ---------------------------------------------------------------------------
// fp16 MFMA flash attention. Block = 4 waves, 64 Q-rows, one (b,h). 16 K-tiles.
// Swapped QK^T single-pass fp16; PV fp16. Emits hi/lo bf16 x for the O-GEMM.
// ---------------------------------------------------------------------------
__global__ __launch_bounds__(256)
void attn_f16(const unsigned short* __restrict__ Qh, const unsigned short* __restrict__ Kh,
              const unsigned short* __restrict__ Vt,
              unsigned short* __restrict__ Xbh, unsigned short* __restrict__ Xbl)
{
    __shared__ _Float16 sK[64][72];
    __shared__ _Float16 sV[64][72];
    __shared__ _Float16 sP[4][16][72];

    const int tid  = threadIdx.x;
    const int lane = tid & 63;
    const int wv   = tid >> 6;
    const int c    = lane & 15;
    const int g    = lane >> 4;

    const int bh = blockIdx.y;
    const int q0 = blockIdx.x * 64;
    const size_t hb = (size_t)bh * (N_DIM * HD);

    const size_t qoff = hb + (size_t)(q0 + wv * 16 + c) * HD;
    f16x8 q0f = *(const f16x8*)(Qh + qoff + 8 * g);
    f16x8 q1f = *(const f16x8*)(Qh + qoff + 32 + 8 * g);

    f32x4 acc[4] = {};
    float m_st = -3.0e38f, l_st = 0.0f;

    for (int kt = 0; kt < 16; ++kt) {
        __syncthreads();
        #pragma unroll
        for (int it = 0; it < 2; ++it) {
            int f = tid + it * 256;      // 0..511
            int row = f >> 3;
            int ch = (f & 7) * 8;
            *(s16x8*)&sK[row][ch] = *(const s16x8*)(Kh + hb + (size_t)(kt * 64 + row) * HD + ch);
            *(s16x8*)&sV[row][ch] = *(const s16x8*)(Vt + hb + (size_t)row * N_DIM + kt * 64 + ch);
        }
        __syncthreads();

        // St = K * Q^T single-pass fp16
        f32x4 s[4] = {};
        __builtin_amdgcn_s_setprio(1);
        #pragma unroll
        for (int st = 0; st < 4; ++st) {
            f16x8 a0 = *(const f16x8*)&sK[16 * st + c][8 * g];
            f16x8 a1 = *(const f16x8*)&sK[16 * st + c][32 + 8 * g];
            s[st] = __builtin_amdgcn_mfma_f32_16x16x32_f16(a0, q0f, s[st], 0, 0, 0);
            s[st] = __builtin_amdgcn_mfma_f32_16x16x32_f16(a1, q1f, s[st], 0, 0, 0);
        }
        __builtin_amdgcn_s_setprio(0);

        // online softmax over k (16 vals/lane for q=c; reduce over 4 g-lanes)
        float pm = -3.0e38f;
        #pragma unroll
        for (int st = 0; st < 4; ++st)
            #pragma unroll
            for (int r = 0; r < 4; ++r)
                pm = fmaxf(pm, s[st][r]);
        pm = fmaxf(pm, __shfl_xor(pm, 16, 64));
        pm = fmaxf(pm, __shfl_xor(pm, 32, 64));
        float mnew = fmaxf(m_st, pm);
        float alpha = __expf(m_st - mnew);
        float p[4][4];
        float rs = 0.0f;
        #pragma unroll
        for (int st = 0; st < 4; ++st)
            #pragma unroll
            for (int r = 0; r < 4; ++r) {
                p[st][r] = __expf(s[st][r] - mnew);
                rs += p[st][r];
            }
        rs += __shfl_xor(rs, 16, 64);
        rs += __shfl_xor(rs, 32, 64);
        l_st = alpha * l_st + rs;
        m_st = mnew;
        #pragma unroll
        for (int sd = 0; sd < 4; ++sd)
            acc[sd] *= alpha;

        // P -> fp16 -> wave-private LDS [q=c][k], k = 16st + 4g + r
        #pragma unroll
        for (int st = 0; st < 4; ++st) {
            unsigned w0 = (unsigned)f2h(p[st][0]) | ((unsigned)f2h(p[st][1]) << 16);
            unsigned w1 = (unsigned)f2h(p[st][2]) | ((unsigned)f2h(p[st][3]) << 16);
            *(uint2*)&sP[wv][c][16 * st + 4 * g] = make_uint2(w0, w1);
        }

        // x^T += V^T * P
        __builtin_amdgcn_s_setprio(1);
        #pragma unroll
        for (int m = 0; m < 2; ++m) {
            f16x8 pb = *(const f16x8*)&sP[wv][c][32 * m + 8 * g];
            #pragma unroll
            for (int sd = 0; sd < 4; ++sd) {
                f16x8 va = *(const f16x8*)&sV[16 * sd + c][32 * m + 8 * g];
                acc[sd] = __builtin_amdgcn_mfma_f32_16x16x32_f16(va, pb, acc[sd], 0, 0, 0);
            }
        }
        __builtin_amdgcn_s_setprio(0);
    }

    // normalize + write hi/lo bf16 x in (B,N,C)
    const int b = bh / H_DIM, h = bh % H_DIM;
    const int q = q0 + wv * 16 + c;
    float invl = 1.0f / l_st;
    size_t obase = ((size_t)(b * N_DIM + q)) * C_DIM + h * HD;
    #pragma unroll
    for (int sd = 0; sd < 4; ++sd) {
        unsigned short hs[4], ls[4];
        #pragma unroll
        for (int r = 0; r < 4; ++r) {
            float o = acc[sd][r] * invl;
            hs[r] = f2bf(o);
            ls[r] = f2bf(o - bf2f(hs[r]));
        }
        *(uint2*)(Xbh + obase + 16 * sd + 4 * g) =
            make_uint2((unsigned)hs[0] | ((unsigned)hs[1] << 16),
                       (unsigned)hs[2] | ((unsigned)hs[3] << 16));
        *(uint2*)(Xbl + obase + 16 * sd + 4 * g) =
            make_uint2((unsigned)ls[0] | ((unsigned)ls[1] << 16),
                       (unsigned)ls[2] | ((unsigned)ls[3] << 16));
    }
}

// ---------------------------------------------------------------------------
extern "C" void kernel_launch(void* const* d_in, const int* in_sizes, int n_in,
                              void* d_out, int out_size, void* d_ws, size_t ws_size,
                              hipStream_t stream)
{
    const float* query = (const float*)d_in[0];
    const float* key_  = (const float*)d_in[1];
    const float* value = (const float*)d_in[2];
    const int*   qpos  = (const int*)d_in[3];
    const int*   kpos  = (const int*)d_in[4];
    const float* Wq    = (const float*)d_in[5];
    const float* Wk    = (const float*)d_in[6];
    const float* Wv    = (const float*)d_in[7];
    const float* Wo    = (const float*)d_in[8];
    const float* bo    = (const float*)d_in[9];
    float* out = (float*)d_out;

    unsigned short* XS  = (unsigned short*)d_ws;     // 6 x TEN (bf16 hi/lo q,k,v)
    unsigned short* WS  = XS + 6 * TEN;              // 8 x WN  (bf16 hi/lo Wq..Wo)
    unsigned short* Qh  = WS + 8 * WN;               // fp16 head layout
    unsigned short* Kh  = Qh + TEN;
    unsigned short* Vf  = Kh + TEN;                  // fp16 (B,N,C)
    unsigned short* Vt  = Vf + TEN;                  // fp16 (B,H,64,N)
    unsigned short* Xbh = Vt + TEN;                  // bf16 hi
    unsigned short* Xbl = Xbh + TEN;                 // bf16 lo
    float2* tab = (float2*)(Xbl + TEN);              // 512 float2

    angles512<<<1, 512, 0, stream>>>(tab);
    splitX<<<dim3((unsigned)(TEN / 8 / 256), 3), 256, 0, stream>>>(query, key_, value, XS);
    splitW<<<dim3((unsigned)(WN / 8 / 256), 4), 256, 0, stream>>>(Wq, Wk, Wv, Wo, WS);

    gemm3<1><<<dim3(M_DIM / 128, C_DIM / 128, 3), 256, 0, stream>>>(
        XS + 0 * TEN, XS + 1 * TEN, XS + 2 * TEN, XS + 3 * TEN, XS + 4 * TEN, XS + 5 * TEN,
        WS + 0 * WN, WS + 1 * WN, WS + 2 * WN, WS + 3 * WN, WS + 4 * WN, WS + 5 * WN,
        qpos, kpos, tab, Qh, Kh, Vf, nullptr, nullptr);

    vtrans<<<dim3(N_DIM / 64, BH), 256, 0, stream>>>(Vf, Vt);

    attn_f16<<<dim3(N_DIM / 64, BH), 256, 0, stream>>>(Qh, Kh, Vt, Xbh, Xbl);

    gemm3<0><<<dim3(M_DIM / 128, C_DIM / 128, 1), 256, 0, stream>>>(
        Xbh, Xbl, nullptr, nullptr, nullptr, nullptr,
        WS + 6 * WN, WS + 7 * WN, nullptr, nullptr, nullptr, nullptr,
        nullptr, nullptr, nullptr, nullptr, nullptr, nullptr, bo, out);
}